// Round 7
// baseline (346.510 us; speedup 1.0000x reference)
//
#include <hip/hip_runtime.h>
#include <stdint.h>

// ---------------------------------------------------------------------------
// CTBG circuit, round 7.
//   Weight side (unchanged from r6):
//     wc_nt[i][u] = wi_topnt[i][u] + sum_j we_nt[i][j]*wi_bot[u][j]
//     w1ct[n][i]  = sum_u w1t[n][u]*wc_nt[i][u]
//     b1c[n]      = (gpi_b + gpe_b @ WiBot) @ w1 + b1
//   Batch side:
//     h1 = relu(x @ W1c + b1c)  -- NEW gemm_x32: 32m x 512n tile, x fetched
//        exactly once, f32->bf16 fused into staging with 1-step reg prefetch
//     h2 = relu(h1 @ w2 + b2)    gemm_bt 128x128 (m97 structure)
//     out = relu(h2 @ w3 + b3)   head
// 6 launches: prep_all, combo1, combo2, gemm_x32, gemm_bt, head.
// ---------------------------------------------------------------------------

typedef __attribute__((ext_vector_type(8))) short short8;
typedef __attribute__((ext_vector_type(4))) float floatx4;

typedef const __attribute__((address_space(1))) void* gas1_cvp;
typedef __attribute__((address_space(3))) void* gas3_vp;

__device__ __forceinline__ void load_lds16(const void* g, void* s) {
    __builtin_amdgcn_global_load_lds((gas1_cvp)g, (gas3_vp)s, 16, 0, 0);
}

__device__ __forceinline__ unsigned short f2bf(float f) {
    unsigned int u = __float_as_uint(f);
    u = u + 0x7fffu + ((u >> 16) & 1u);          // RNE
    return (unsigned short)(u >> 16);
}
__device__ __forceinline__ float bf2f(unsigned short h) {
    return __uint_as_float(((unsigned int)h) << 16);
}

// ---------------------------------------------------------------------------
// Prep bodies. Block = 256 threads.
// Transposing: out[n][k] = bf16( w[k][n] * (mask ? mask[n][k] : 1) )
// ---------------------------------------------------------------------------
__device__ __forceinline__ void dev_prep_t(
        float (*tile)[65],
        const float* __restrict__ w, const float* __restrict__ mask,
        unsigned short* __restrict__ out,
        int ldw, int ldm, int ldo, int bx, int by) {
    int n0 = bx * 64;
    int k0 = by * 64;
    int t = threadIdx.x;
    int c4 = (t & 15) * 4;
    int r  = t >> 4;

    #pragma unroll
    for (int p = 0; p < 4; ++p) {
        int kk = r + p * 16;
        float4 v = *(const float4*)(w + (size_t)(k0 + kk) * ldw + n0 + c4);
        tile[c4 + 0][kk] = v.x;
        tile[c4 + 1][kk] = v.y;
        tile[c4 + 2][kk] = v.z;
        tile[c4 + 3][kk] = v.w;
    }
    __syncthreads();
    #pragma unroll
    for (int p = 0; p < 4; ++p) {
        int nn = r + p * 16;
        float mx = 1.f, my = 1.f, mz = 1.f, mw = 1.f;
        if (mask) {
            float4 m = *(const float4*)(mask + (size_t)(n0 + nn) * ldm + k0 + c4);
            mx = m.x; my = m.y; mz = m.z; mw = m.w;
        }
        ushort4 o;
        o.x = f2bf(tile[nn][c4 + 0] * mx);
        o.y = f2bf(tile[nn][c4 + 1] * my);
        o.z = f2bf(tile[nn][c4 + 2] * mz);
        o.w = f2bf(tile[nn][c4 + 3] * mw);
        *(ushort4*)(out + (size_t)(n0 + nn) * ldo + k0 + c4) = o;
    }
}

// Non-transposing: out[i][j] = bf16( w[i][j] * mask[j][i] )
__device__ __forceinline__ void dev_prep_nt(
        float (*tile)[65],
        const float* __restrict__ w, const float* __restrict__ mask,
        unsigned short* __restrict__ out,
        int ldw, int ldm, int ldo, int bx, int by) {
    int j0 = bx * 64;
    int i0 = by * 64;
    int t = threadIdx.x;
    int c4 = (t & 15) * 4;
    int r  = t >> 4;

    #pragma unroll
    for (int p = 0; p < 4; ++p) {
        int jj = r + p * 16;
        float4 m = *(const float4*)(mask + (size_t)(j0 + jj) * ldm + i0 + c4);
        tile[c4 + 0][jj] = m.x;
        tile[c4 + 1][jj] = m.y;
        tile[c4 + 2][jj] = m.z;
        tile[c4 + 3][jj] = m.w;
    }
    __syncthreads();
    #pragma unroll
    for (int p = 0; p < 4; ++p) {
        int ii = r + p * 16;
        float4 v = *(const float4*)(w + (size_t)(i0 + ii) * ldw + j0 + c4);
        ushort4 o;
        o.x = f2bf(v.x * tile[ii][c4 + 0]);
        o.y = f2bf(v.y * tile[ii][c4 + 1]);
        o.z = f2bf(v.z * tile[ii][c4 + 2]);
        o.w = f2bf(v.w * tile[ii][c4 + 3]);
        *(ushort4*)(out + (size_t)(i0 + ii) * ldo + j0 + c4) = o;
    }
}

// One kernel for all 5 weight preps, flattened 1D grid (1984 blocks).
__global__ __launch_bounds__(256) void prep_all_kernel(
        const float* __restrict__ gpe_w, const float* __restrict__ gpe_mask,
        const float* __restrict__ gpi_w, const float* __restrict__ gpi_mask,
        const float* __restrict__ w1, const float* __restrict__ w2,
        unsigned short* __restrict__ wi_topnt, unsigned short* __restrict__ wi_bot,
        unsigned short* __restrict__ we_nt, unsigned short* __restrict__ w1t,
        unsigned short* __restrict__ w2t) {
    __shared__ float tile[64][65];
    int b = blockIdx.x;
    if (b < 576) {
        dev_prep_nt(tile, gpi_w, gpi_mask, wi_topnt, 1536, 3072, 1536,
                    b % 24, b / 24);
    } else if (b < 1152) {
        int lb = b - 576;
        dev_prep_t(tile, gpi_w + (size_t)1536 * 1536, gpi_mask + 1536, wi_bot,
                   1536, 3072, 1536, lb % 24, lb / 24);
    } else if (b < 1728) {
        int lb = b - 1152;
        dev_prep_nt(tile, gpe_w, gpe_mask, we_nt, 1536, 1536, 1536,
                    lb % 24, lb / 24);
    } else if (b < 1920) {
        int lb = b - 1728;
        dev_prep_t(tile, w1, nullptr, w1t, 512, 0, 1536, lb % 8, lb / 8);
    } else {
        int lb = b - 1920;
        dev_prep_t(tile, w2, nullptr, w2t, 512, 0, 512, lb % 8, lb / 8);
    }
}

// ---------------------------------------------------------------------------
// bvec body: outv[u] = base[u] + sum_j avec[j] * wbt[u][j]  (one wave per u)
// ---------------------------------------------------------------------------
__device__ __forceinline__ void dev_bvec(
        const float* __restrict__ avec, const float* __restrict__ base,
        const unsigned short* __restrict__ wbt, float* __restrict__ outv,
        int K, int ld, int blk) {
    int u = blk * 4 + (threadIdx.x >> 6);
    int lane = threadIdx.x & 63;
    const unsigned short* rowp = wbt + (size_t)u * ld;
    float s = 0.f;
    for (int j = lane; j < K; j += 64) s += avec[j] * bf2f(rowp[j]);
    #pragma unroll
    for (int off = 32; off; off >>= 1) s += __shfl_down(s, off, 64);
    if (lane == 0) outv[u] = base[u] + s;
}

// ---------------------------------------------------------------------------
// 64x64-tile GEMM body for the tiny weight combines.
// BMODE: 1 = +Add[m][n], 2 = nothing.
// ---------------------------------------------------------------------------
template <int BMODE>
__device__ __forceinline__ void dev_gemm64(
        unsigned short* As, unsigned short* Bs,
        const unsigned short* __restrict__ A,
        const unsigned short* __restrict__ Bt,
        const unsigned short* __restrict__ Add,
        unsigned short* __restrict__ C,
        int K, int lda, int ldc, int bx, int by) {
    const int m0 = by * 64;
    const int n0 = bx * 64;
    const int t    = threadIdx.x;
    const int lane = t & 63;
    const int w    = t >> 6;
    const int wm   = w >> 1;
    const int wn   = w & 1;
    const int lm   = lane & 15;
    const int lq   = lane >> 4;

    const int srow = lane >> 2;
    const int scol = (lane & 3) * 8;
    const unsigned short* ag = A  + (size_t)(m0 + w * 16 + srow) * lda + scol;
    const unsigned short* bg = Bt + (size_t)(n0 + w * 16 + srow) * K + scol;
    unsigned short* sA = As + w * 512;
    unsigned short* sB = Bs + w * 512;

    const unsigned short* arp[2];
    const unsigned short* brp[2];
    #pragma unroll
    for (int i = 0; i < 2; ++i) {
        arp[i] = As + (wm * 32 + i * 16 + lm) * 32 + lq * 8;
        brp[i] = Bs + (wn * 32 + i * 16 + lm) * 32 + lq * 8;
    }

    floatx4 acc[2][2] = {};

    for (int k0 = 0; k0 < K; k0 += 32) {
        __syncthreads();
        load_lds16(ag + k0, sA);
        load_lds16(bg + k0, sB);
        __syncthreads();

        short8 af[2], bf8[2];
        #pragma unroll
        for (int i = 0; i < 2; ++i) {
            af[i]  = *(const short8*)arp[i];
            bf8[i] = *(const short8*)brp[i];
        }
        #pragma unroll
        for (int mi = 0; mi < 2; ++mi)
            #pragma unroll
            for (int ni = 0; ni < 2; ++ni)
                acc[mi][ni] = __builtin_amdgcn_mfma_f32_16x16x32_bf16(
                    af[mi], bf8[ni], acc[mi][ni], 0, 0, 0);
    }

    #pragma unroll
    for (int mi = 0; mi < 2; ++mi) {
        int rbase = m0 + wm * 32 + mi * 16 + lq * 4;
        #pragma unroll
        for (int ni = 0; ni < 2; ++ni) {
            int cc = n0 + wn * 32 + ni * 16 + lm;
            #pragma unroll
            for (int r = 0; r < 4; ++r) {
                float v = acc[mi][ni][r];
                if (BMODE == 1) v += bf2f(Add[(size_t)(rbase + r) * ldc + cc]);
                C[(size_t)(rbase + r) * ldc + cc] = f2bf(v);
            }
        }
    }
}

// combo1: blocks [0,576) = combine1 (wc_nt), [576,960) = bvec1 (bc)
__global__ __launch_bounds__(256) void combo1_kernel(
        const unsigned short* __restrict__ we_nt,
        const unsigned short* __restrict__ wi_bot,
        const unsigned short* __restrict__ wi_topnt,
        unsigned short* __restrict__ wc_nt,
        const float* __restrict__ gpe_b, const float* __restrict__ gpi_b,
        float* __restrict__ bc) {
    __shared__ unsigned short As[64 * 32];
    __shared__ unsigned short Bs[64 * 32];
    int b = blockIdx.x;
    if (b < 576) {
        dev_gemm64<1>(As, Bs, we_nt, wi_bot, wi_topnt, wc_nt,
                      1536, 1536, 1536, b % 24, b / 24);
    } else {
        dev_bvec(gpe_b, gpi_b, wi_bot, bc, 1536, 1536, b - 576);
    }
}

// combo2: blocks [0,192) = combine2 (w1ct), [192,320) = bvec2 (b1c)
__global__ __launch_bounds__(256) void combo2_kernel(
        const unsigned short* __restrict__ w1t,
        const unsigned short* __restrict__ wc_nt,
        unsigned short* __restrict__ w1ct,
        const float* __restrict__ bc, const float* __restrict__ b1,
        float* __restrict__ b1c) {
    __shared__ unsigned short As[64 * 32];
    __shared__ unsigned short Bs[64 * 32];
    int b = blockIdx.x;
    if (b < 192) {
        dev_gemm64<2>(As, Bs, w1t, wc_nt, nullptr, w1ct,
                      1536, 1536, 1536, b % 24, b / 24);
    } else {
        dev_bvec(bc, b1, w1t, b1c, 1536, 1536, b - 192);
    }
}

// ---------------------------------------------------------------------------
// h1 GEMM: 32m x 512n tile per block (full N) -> x fetched from HBM exactly
// once. A is fp32, converted to bf16 during staging with a one-K-step
// register prefetch so the HBM latency overlaps the previous step's MFMAs.
// Waves: 4 side-by-side, each owns 128 n-cols (2x8 MFMA 16x16x32 per K-step).
// ---------------------------------------------------------------------------
__global__ __launch_bounds__(256) void gemm_x32_kernel(
        const float* __restrict__ A,            // [16384][1536] fp32
        const unsigned short* __restrict__ Bt,  // [512][1536]  bf16
        const float* __restrict__ bias,         // [512]
        unsigned short* __restrict__ C) {       // [16384][512] bf16
    __shared__ unsigned short As[32 * 32];      //  2 KB
    __shared__ unsigned short Bs[512 * 32];     // 32 KB

    const int m0   = blockIdx.x * 32;
    const int t    = threadIdx.x;
    const int lane = t & 63;
    const int w    = t >> 6;
    const int lm   = lane & 15;
    const int lq   = lane >> 4;

    // A staging: thread t -> row t>>3 (0..31), col (t&7)*4 (float4)
    const int arow = t >> 3;
    const int acol = (t & 7) * 4;
    const float* ag = A + (size_t)(m0 + arow) * 1536 + acol;
    unsigned short* sAw = As + arow * 32 + acol;

    // B staging: wave w stages rows [w*128, w*128+128) in 8 chunks of 16 rows
    const int srow = lane >> 2;
    const int scol = (lane & 3) * 8;
    const unsigned short* bg[8];
    #pragma unroll
    for (int c = 0; c < 8; ++c)
        bg[c] = Bt + (size_t)(w * 128 + c * 16 + srow) * 1536 + scol;

    floatx4 acc[2][8] = {};

    float4 apre = *(const float4*)(ag);         // prefetch k0 = 0

    for (int k0 = 0; k0 < 1536; k0 += 32) {
        __syncthreads();
        #pragma unroll
        for (int c = 0; c < 8; ++c)
            load_lds16(bg[c] + k0, Bs + (w * 128 + c * 16) * 32);
        // write prefetched A tile (bf16) and prefetch the next one
        ushort4 o;
        o.x = f2bf(apre.x); o.y = f2bf(apre.y);
        o.z = f2bf(apre.z); o.w = f2bf(apre.w);
        *(ushort4*)sAw = o;
        int kn = (k0 + 32 < 1536) ? k0 + 32 : 0;
        apre = *(const float4*)(ag + kn);
        __syncthreads();

        short8 af[2], bf8[8];
        #pragma unroll
        for (int i = 0; i < 2; ++i)
            af[i] = *(const short8*)(As + (i * 16 + lm) * 32 + lq * 8);
        #pragma unroll
        for (int i = 0; i < 8; ++i)
            bf8[i] = *(const short8*)(Bs + (w * 128 + i * 16 + lm) * 32 + lq * 8);
        #pragma unroll
        for (int mi = 0; mi < 2; ++mi)
            #pragma unroll
            for (int ni = 0; ni < 8; ++ni)
                acc[mi][ni] = __builtin_amdgcn_mfma_f32_16x16x32_bf16(
                    af[mi], bf8[ni], acc[mi][ni], 0, 0, 0);
    }

    float bv[8];
    #pragma unroll
    for (int ni = 0; ni < 8; ++ni) bv[ni] = bias[w * 128 + ni * 16 + lm];

    #pragma unroll
    for (int mi = 0; mi < 2; ++mi) {
        int rbase = m0 + mi * 16 + lq * 4;
        #pragma unroll
        for (int ni = 0; ni < 8; ++ni) {
            int cc = w * 128 + ni * 16 + lm;
            #pragma unroll
            for (int r = 0; r < 4; ++r) {
                float v = fmaxf(acc[mi][ni][r] + bv[ni], 0.f);
                C[(size_t)(rbase + r) * 512 + cc] = f2bf(v);
            }
        }
    }
}

// ---------------------------------------------------------------------------
// 128x128-tile GEMM (m97 structure), bf16 A and B: C = relu(A@Bt^T + bias).
// ---------------------------------------------------------------------------
__global__ __launch_bounds__(256) void gemm_bt_kernel(
        const unsigned short* __restrict__ A,
        const unsigned short* __restrict__ Bt,
        const float* __restrict__ bias,
        unsigned short* __restrict__ C,
        int K, int lda, int ldc) {
    __shared__ unsigned short As[128 * 32];
    __shared__ unsigned short Bs[128 * 32];

    const int m0 = blockIdx.y * 128;
    const int n0 = blockIdx.x * 128;
    const int t    = threadIdx.x;
    const int lane = t & 63;
    const int w    = t >> 6;
    const int wm   = w >> 1;
    const int wn   = w & 1;
    const int lm   = lane & 15;
    const int lq   = lane >> 4;

    const int srow = lane >> 2;
    const int scol = (lane & 3) * 8;
    const unsigned short* ag0 = A  + (size_t)(m0 + w * 16 + srow) * lda + scol;
    const unsigned short* ag1 = A  + (size_t)(m0 + (4 + w) * 16 + srow) * lda + scol;
    const unsigned short* bg0 = Bt + (size_t)(n0 + w * 16 + srow) * K + scol;
    const unsigned short* bg1 = Bt + (size_t)(n0 + (4 + w) * 16 + srow) * K + scol;
    unsigned short* sA0 = As + w * 512;
    unsigned short* sA1 = As + (4 + w) * 512;
    unsigned short* sB0 = Bs + w * 512;
    unsigned short* sB1 = Bs + (4 + w) * 512;

    const unsigned short* arp[4];
    const unsigned short* brp[4];
    #pragma unroll
    for (int i = 0; i < 4; ++i) {
        arp[i] = As + (wm * 64 + i * 16 + lm) * 32 + lq * 8;
        brp[i] = Bs + (wn * 64 + i * 16 + lm) * 32 + lq * 8;
    }

    floatx4 acc[4][4] = {};

    for (int k0 = 0; k0 < K; k0 += 32) {
        __syncthreads();
        load_lds16(ag0 + k0, sA0);
        load_lds16(ag1 + k0, sA1);
        load_lds16(bg0 + k0, sB0);
        load_lds16(bg1 + k0, sB1);
        __syncthreads();

        short8 af[4], bf8[4];
        #pragma unroll
        for (int i = 0; i < 4; ++i) {
            af[i]  = *(const short8*)arp[i];
            bf8[i] = *(const short8*)brp[i];
        }
        #pragma unroll
        for (int mi = 0; mi < 4; ++mi)
            #pragma unroll
            for (int ni = 0; ni < 4; ++ni)
                acc[mi][ni] = __builtin_amdgcn_mfma_f32_16x16x32_bf16(
                    af[mi], bf8[ni], acc[mi][ni], 0, 0, 0);
    }

    float bv[4];
    #pragma unroll
    for (int ni = 0; ni < 4; ++ni) bv[ni] = bias[n0 + wn * 64 + ni * 16 + lm];

    #pragma unroll
    for (int mi = 0; mi < 4; ++mi) {
        int rbase = m0 + wm * 64 + mi * 16 + lq * 4;
        #pragma unroll
        for (int ni = 0; ni < 4; ++ni) {
            int cc = n0 + wn * 64 + ni * 16 + lm;
            #pragma unroll
            for (int r = 0; r < 4; ++r) {
                float v = fmaxf(acc[mi][ni][r] + bv[ni], 0.f);
                C[(size_t)(rbase + r) * ldc + cc] = f2bf(v);
            }
        }
    }
}

// ---------------------------------------------------------------------------
// head: one wave per row, 16B/lane coalesced, shuffle-reduce 6 sums.
// ---------------------------------------------------------------------------
__global__ void head_kernel(const unsigned short* __restrict__ h,
                            const float* __restrict__ w3,
                            const float* __restrict__ b3,
                            float* __restrict__ out) {
    int row = blockIdx.x * 4 + (threadIdx.x >> 6);
    int lane = threadIdx.x & 63;
    const unsigned short* hp = h + (size_t)row * 512 + lane * 8;
    ushort4 ha = *(const ushort4*)(hp);
    ushort4 hb = *(const ushort4*)(hp + 4);
    float hv[8] = {bf2f(ha.x), bf2f(ha.y), bf2f(ha.z), bf2f(ha.w),
                   bf2f(hb.x), bf2f(hb.y), bf2f(hb.z), bf2f(hb.w)};
    const float* wp = w3 + lane * 48;
    float s[6] = {0.f, 0.f, 0.f, 0.f, 0.f, 0.f};
    #pragma unroll
    for (int j = 0; j < 8; ++j)
        #pragma unroll
        for (int a = 0; a < 6; ++a)
            s[a] += hv[j] * wp[j * 6 + a];
    #pragma unroll
    for (int a = 0; a < 6; ++a)
        #pragma unroll
        for (int off = 32; off; off >>= 1)
            s[a] += __shfl_down(s[a], off, 64);
    if (lane == 0) {
        #pragma unroll
        for (int a = 0; a < 6; ++a)
            out[(size_t)row * 6 + a] = fmaxf(s[a] + b3[a], 0.f);
    }
}

// ---------------------------------------------------------------------------
extern "C" void kernel_launch(void* const* d_in, const int* in_sizes, int n_in,
                              void* d_out, int out_size, void* d_ws, size_t ws_size,
                              hipStream_t stream) {
    const float* x        = (const float*)d_in[0];
    const float* gpe_mask = (const float*)d_in[1];
    const float* gpe_w    = (const float*)d_in[2];
    const float* gpe_b    = (const float*)d_in[3];
    const float* gpi_mask = (const float*)d_in[4];
    const float* gpi_w    = (const float*)d_in[5];
    const float* gpi_b    = (const float*)d_in[6];
    const float* w1       = (const float*)d_in[7];
    const float* b1       = (const float*)d_in[8];
    const float* w2       = (const float*)d_in[9];
    const float* b2       = (const float*)d_in[10];
    const float* w3       = (const float*)d_in[11];
    const float* b3       = (const float*)d_in[12];
    float* out = (float*)d_out;

    // workspace carve (bytes), total ~56.1 MB
    char* ws = (char*)d_ws;
    unsigned short* h1        = (unsigned short*)(ws);              // B*512
    unsigned short* h2        = (unsigned short*)(ws + 16777216);   // B*512
    unsigned short* wi_topnt  = (unsigned short*)(ws + 33554432);   // [i][u] 1536^2
    unsigned short* wi_bot    = (unsigned short*)(ws + 38273024);   // [u][j] 1536^2
    unsigned short* we_nt     = (unsigned short*)(ws + 42991616);   // [i][j] 1536^2
    unsigned short* wc_nt     = (unsigned short*)(ws + 47710208);   // [i][u] 1536^2
    unsigned short* w1t       = (unsigned short*)(ws + 52428800);   // [n][u] 512x1536
    unsigned short* w2t       = (unsigned short*)(ws + 54001664);   // [n][k] 512x512
    unsigned short* w1ct      = (unsigned short*)(ws + 54525952);   // [n][i] 512x1536
    float*          bc        = (float*)(ws + 56098816);            // [1536]
    float*          b1c       = (float*)(ws + 56104960);            // [512]

    // ---- weight preps ----
    prep_all_kernel<<<dim3(1984), dim3(256), 0, stream>>>(
        gpe_w, gpe_mask, gpi_w, gpi_mask, w1, w2,
        wi_topnt, wi_bot, we_nt, w1t, w2t);

    // ---- combine1 + bias-fold1 ----
    combo1_kernel<<<dim3(960), dim3(256), 0, stream>>>(
        we_nt, wi_bot, wi_topnt, wc_nt, gpe_b, gpi_b, bc);

    // ---- combine2 + bias-fold2 ----
    combo2_kernel<<<dim3(320), dim3(256), 0, stream>>>(
        w1t, wc_nt, w1ct, bc, b1, b1c);

    // ---- batch chain ----
    // h1 = relu(x @ W1c + b1c): full-N tile, x fetched once, fused cvt
    gemm_x32_kernel<<<dim3(512), dim3(256), 0, stream>>>(x, w1ct, b1c, h1);
    // h2 = relu(h1 @ w2 + b2)
    gemm_bt_kernel<<<dim3(4, 128), dim3(256), 0, stream>>>(
        h1, w2t, b2, h2, 512, 512, 512);
    // out = relu(h2 @ w3 + b3)
    head_kernel<<<dim3(16384 / 4), dim3(256), 0, stream>>>(h2, w3, b3, out);
}

// Round 8
// 334.124 us; speedup vs baseline: 1.0371x; 1.0371x over previous
//
#include <hip/hip_runtime.h>
#include <stdint.h>

// ---------------------------------------------------------------------------
// CTBG circuit, round 8 = round 6 + one-K-step register prefetch of A in
// gemm_a32 (the only structural flaw r6 had: f32 A loads were consumed in the
// same K-step, exposing full HBM latency each iteration; r7 proved prefetch
// helps but wrecked the staging ratio with a full-N tile).
//   Weight side:
//     wc_nt[i][u] = wi_topnt[i][u] + sum_j we_nt[i][j]*wi_bot[u][j]
//     w1ct[n][i]  = sum_u w1t[n][u]*wc_nt[i][u]
//     b1c[n]      = (gpi_b + gpe_b @ WiBot) @ w1 + b1
//   Batch side:
//     h1 = relu(x @ W1c + b1c)   gemm_a32 128x128 (fused f32->bf16, prefetch)
//     h2 = relu(h1 @ w2 + b2)    gemm_bt 128x128 (m97 structure)
//     out = relu(h2 @ w3 + b3)   head
// ---------------------------------------------------------------------------

typedef __attribute__((ext_vector_type(8))) short short8;
typedef __attribute__((ext_vector_type(4))) float floatx4;

typedef const __attribute__((address_space(1))) void* gas1_cvp;
typedef __attribute__((address_space(3))) void* gas3_vp;

__device__ __forceinline__ void load_lds16(const void* g, void* s) {
    __builtin_amdgcn_global_load_lds((gas1_cvp)g, (gas3_vp)s, 16, 0, 0);
}

__device__ __forceinline__ unsigned short f2bf(float f) {
    unsigned int u = __float_as_uint(f);
    u = u + 0x7fffu + ((u >> 16) & 1u);          // RNE
    return (unsigned short)(u >> 16);
}
__device__ __forceinline__ float bf2f(unsigned short h) {
    return __uint_as_float(((unsigned int)h) << 16);
}
__device__ __forceinline__ short8 cvt8(float4 a, float4 b) {
    short8 r;
    r[0] = (short)f2bf(a.x); r[1] = (short)f2bf(a.y);
    r[2] = (short)f2bf(a.z); r[3] = (short)f2bf(a.w);
    r[4] = (short)f2bf(b.x); r[5] = (short)f2bf(b.y);
    r[6] = (short)f2bf(b.z); r[7] = (short)f2bf(b.w);
    return r;
}

// ---------------------------------------------------------------------------
// Prep bodies. Block = 256 threads.
// Transposing: out[n][k] = bf16( w[k][n] * (mask ? mask[n][k] : 1) )
// ---------------------------------------------------------------------------
__device__ __forceinline__ void dev_prep_t(
        float (*tile)[65],
        const float* __restrict__ w, const float* __restrict__ mask,
        unsigned short* __restrict__ out,
        int ldw, int ldm, int ldo, int bx, int by) {
    int n0 = bx * 64;
    int k0 = by * 64;
    int t = threadIdx.x;
    int c4 = (t & 15) * 4;
    int r  = t >> 4;

    #pragma unroll
    for (int p = 0; p < 4; ++p) {
        int kk = r + p * 16;
        float4 v = *(const float4*)(w + (size_t)(k0 + kk) * ldw + n0 + c4);
        tile[c4 + 0][kk] = v.x;
        tile[c4 + 1][kk] = v.y;
        tile[c4 + 2][kk] = v.z;
        tile[c4 + 3][kk] = v.w;
    }
    __syncthreads();
    #pragma unroll
    for (int p = 0; p < 4; ++p) {
        int nn = r + p * 16;
        float mx = 1.f, my = 1.f, mz = 1.f, mw = 1.f;
        if (mask) {
            float4 m = *(const float4*)(mask + (size_t)(n0 + nn) * ldm + k0 + c4);
            mx = m.x; my = m.y; mz = m.z; mw = m.w;
        }
        ushort4 o;
        o.x = f2bf(tile[nn][c4 + 0] * mx);
        o.y = f2bf(tile[nn][c4 + 1] * my);
        o.z = f2bf(tile[nn][c4 + 2] * mz);
        o.w = f2bf(tile[nn][c4 + 3] * mw);
        *(ushort4*)(out + (size_t)(n0 + nn) * ldo + k0 + c4) = o;
    }
}

// Non-transposing: out[i][j] = bf16( w[i][j] * mask[j][i] )
__device__ __forceinline__ void dev_prep_nt(
        float (*tile)[65],
        const float* __restrict__ w, const float* __restrict__ mask,
        unsigned short* __restrict__ out,
        int ldw, int ldm, int ldo, int bx, int by) {
    int j0 = bx * 64;
    int i0 = by * 64;
    int t = threadIdx.x;
    int c4 = (t & 15) * 4;
    int r  = t >> 4;

    #pragma unroll
    for (int p = 0; p < 4; ++p) {
        int jj = r + p * 16;
        float4 m = *(const float4*)(mask + (size_t)(j0 + jj) * ldm + i0 + c4);
        tile[c4 + 0][jj] = m.x;
        tile[c4 + 1][jj] = m.y;
        tile[c4 + 2][jj] = m.z;
        tile[c4 + 3][jj] = m.w;
    }
    __syncthreads();
    #pragma unroll
    for (int p = 0; p < 4; ++p) {
        int ii = r + p * 16;
        float4 v = *(const float4*)(w + (size_t)(i0 + ii) * ldw + j0 + c4);
        ushort4 o;
        o.x = f2bf(v.x * tile[ii][c4 + 0]);
        o.y = f2bf(v.y * tile[ii][c4 + 1]);
        o.z = f2bf(v.z * tile[ii][c4 + 2]);
        o.w = f2bf(v.w * tile[ii][c4 + 3]);
        *(ushort4*)(out + (size_t)(i0 + ii) * ldo + j0 + c4) = o;
    }
}

// One kernel for all 5 weight preps, flattened 1D grid (1984 blocks).
__global__ __launch_bounds__(256) void prep_all_kernel(
        const float* __restrict__ gpe_w, const float* __restrict__ gpe_mask,
        const float* __restrict__ gpi_w, const float* __restrict__ gpi_mask,
        const float* __restrict__ w1, const float* __restrict__ w2,
        unsigned short* __restrict__ wi_topnt, unsigned short* __restrict__ wi_bot,
        unsigned short* __restrict__ we_nt, unsigned short* __restrict__ w1t,
        unsigned short* __restrict__ w2t) {
    __shared__ float tile[64][65];
    int b = blockIdx.x;
    if (b < 576) {
        dev_prep_nt(tile, gpi_w, gpi_mask, wi_topnt, 1536, 3072, 1536,
                    b % 24, b / 24);
    } else if (b < 1152) {
        int lb = b - 576;
        dev_prep_t(tile, gpi_w + (size_t)1536 * 1536, gpi_mask + 1536, wi_bot,
                   1536, 3072, 1536, lb % 24, lb / 24);
    } else if (b < 1728) {
        int lb = b - 1152;
        dev_prep_nt(tile, gpe_w, gpe_mask, we_nt, 1536, 1536, 1536,
                    lb % 24, lb / 24);
    } else if (b < 1920) {
        int lb = b - 1728;
        dev_prep_t(tile, w1, nullptr, w1t, 512, 0, 1536, lb % 8, lb / 8);
    } else {
        int lb = b - 1920;
        dev_prep_t(tile, w2, nullptr, w2t, 512, 0, 512, lb % 8, lb / 8);
    }
}

// ---------------------------------------------------------------------------
// bvec body: outv[u] = base[u] + sum_j avec[j] * wbt[u][j]  (one wave per u)
// ---------------------------------------------------------------------------
__device__ __forceinline__ void dev_bvec(
        const float* __restrict__ avec, const float* __restrict__ base,
        const unsigned short* __restrict__ wbt, float* __restrict__ outv,
        int K, int ld, int blk) {
    int u = blk * 4 + (threadIdx.x >> 6);
    int lane = threadIdx.x & 63;
    const unsigned short* rowp = wbt + (size_t)u * ld;
    float s = 0.f;
    for (int j = lane; j < K; j += 64) s += avec[j] * bf2f(rowp[j]);
    #pragma unroll
    for (int off = 32; off; off >>= 1) s += __shfl_down(s, off, 64);
    if (lane == 0) outv[u] = base[u] + s;
}

// ---------------------------------------------------------------------------
// 64x64-tile GEMM body for the tiny weight combines.
// BMODE: 1 = +Add[m][n], 2 = nothing.
// ---------------------------------------------------------------------------
template <int BMODE>
__device__ __forceinline__ void dev_gemm64(
        unsigned short* As, unsigned short* Bs,
        const unsigned short* __restrict__ A,
        const unsigned short* __restrict__ Bt,
        const unsigned short* __restrict__ Add,
        unsigned short* __restrict__ C,
        int K, int lda, int ldc, int bx, int by) {
    const int m0 = by * 64;
    const int n0 = bx * 64;
    const int t    = threadIdx.x;
    const int lane = t & 63;
    const int w    = t >> 6;
    const int wm   = w >> 1;
    const int wn   = w & 1;
    const int lm   = lane & 15;
    const int lq   = lane >> 4;

    const int srow = lane >> 2;
    const int scol = (lane & 3) * 8;
    const unsigned short* ag = A  + (size_t)(m0 + w * 16 + srow) * lda + scol;
    const unsigned short* bg = Bt + (size_t)(n0 + w * 16 + srow) * K + scol;
    unsigned short* sA = As + w * 512;
    unsigned short* sB = Bs + w * 512;

    const unsigned short* arp[2];
    const unsigned short* brp[2];
    #pragma unroll
    for (int i = 0; i < 2; ++i) {
        arp[i] = As + (wm * 32 + i * 16 + lm) * 32 + lq * 8;
        brp[i] = Bs + (wn * 32 + i * 16 + lm) * 32 + lq * 8;
    }

    floatx4 acc[2][2] = {};

    for (int k0 = 0; k0 < K; k0 += 32) {
        __syncthreads();
        load_lds16(ag + k0, sA);
        load_lds16(bg + k0, sB);
        __syncthreads();

        short8 af[2], bf8[2];
        #pragma unroll
        for (int i = 0; i < 2; ++i) {
            af[i]  = *(const short8*)arp[i];
            bf8[i] = *(const short8*)brp[i];
        }
        #pragma unroll
        for (int mi = 0; mi < 2; ++mi)
            #pragma unroll
            for (int ni = 0; ni < 2; ++ni)
                acc[mi][ni] = __builtin_amdgcn_mfma_f32_16x16x32_bf16(
                    af[mi], bf8[ni], acc[mi][ni], 0, 0, 0);
    }

    #pragma unroll
    for (int mi = 0; mi < 2; ++mi) {
        int rbase = m0 + wm * 32 + mi * 16 + lq * 4;
        #pragma unroll
        for (int ni = 0; ni < 2; ++ni) {
            int cc = n0 + wn * 32 + ni * 16 + lm;
            #pragma unroll
            for (int r = 0; r < 4; ++r) {
                float v = acc[mi][ni][r];
                if (BMODE == 1) v += bf2f(Add[(size_t)(rbase + r) * ldc + cc]);
                C[(size_t)(rbase + r) * ldc + cc] = f2bf(v);
            }
        }
    }
}

// combo1: blocks [0,576) = combine1 (wc_nt), [576,960) = bvec1 (bc)
__global__ __launch_bounds__(256) void combo1_kernel(
        const unsigned short* __restrict__ we_nt,
        const unsigned short* __restrict__ wi_bot,
        const unsigned short* __restrict__ wi_topnt,
        unsigned short* __restrict__ wc_nt,
        const float* __restrict__ gpe_b, const float* __restrict__ gpi_b,
        float* __restrict__ bc) {
    __shared__ unsigned short As[64 * 32];
    __shared__ unsigned short Bs[64 * 32];
    int b = blockIdx.x;
    if (b < 576) {
        dev_gemm64<1>(As, Bs, we_nt, wi_bot, wi_topnt, wc_nt,
                      1536, 1536, 1536, b % 24, b / 24);
    } else {
        dev_bvec(gpe_b, gpi_b, wi_bot, bc, 1536, 1536, b - 576);
    }
}

// combo2: blocks [0,192) = combine2 (w1ct), [192,320) = bvec2 (b1c)
__global__ __launch_bounds__(256) void combo2_kernel(
        const unsigned short* __restrict__ w1t,
        const unsigned short* __restrict__ wc_nt,
        unsigned short* __restrict__ w1ct,
        const float* __restrict__ bc, const float* __restrict__ b1,
        float* __restrict__ b1c) {
    __shared__ unsigned short As[64 * 32];
    __shared__ unsigned short Bs[64 * 32];
    int b = blockIdx.x;
    if (b < 192) {
        dev_gemm64<2>(As, Bs, w1t, wc_nt, nullptr, w1ct,
                      1536, 1536, 1536, b % 24, b / 24);
    } else {
        dev_bvec(bc, b1, w1t, b1c, 1536, 1536, b - 192);
    }
}

// ---------------------------------------------------------------------------
// 128x128-tile GEMM, A in FP32 converted to bf16 during staging, with a
// ONE-K-STEP REGISTER PREFETCH of A (consumed at the next iteration's staging
// write, so HBM latency overlaps this iteration's 16 MFMAs + B-load drain).
// B bf16 via global_load_lds. C = relu(A@Bt^T + bias), bf16 out.
// ---------------------------------------------------------------------------
__global__ __launch_bounds__(256) void gemm_a32_kernel(
        const float* __restrict__ A,            // [M][lda] fp32
        const unsigned short* __restrict__ Bt,  // [N][K]  bf16
        const float* __restrict__ bias,         // [N]
        unsigned short* __restrict__ C,         // [M][ldc] bf16
        int K, int lda, int ldc) {
    __shared__ unsigned short As[128 * 32];
    __shared__ unsigned short Bs[128 * 32];

    const int m0 = blockIdx.y * 128;
    const int n0 = blockIdx.x * 128;
    const int t    = threadIdx.x;
    const int lane = t & 63;
    const int w    = t >> 6;
    const int wm   = w >> 1;
    const int wn   = w & 1;
    const int lm   = lane & 15;
    const int lq   = lane >> 4;

    const int srow = lane >> 2;
    const int scol = (lane & 3) * 8;
    const float* axg0 = A + (size_t)(m0 + w * 16 + srow) * lda + scol;
    const float* axg1 = A + (size_t)(m0 + (4 + w) * 16 + srow) * lda + scol;
    const unsigned short* bg0 = Bt + (size_t)(n0 + w * 16 + srow) * K + scol;
    const unsigned short* bg1 = Bt + (size_t)(n0 + (4 + w) * 16 + srow) * K + scol;
    unsigned short* sA0w = As + (w * 16 + srow) * 32 + scol;        // per-lane
    unsigned short* sA1w = As + ((4 + w) * 16 + srow) * 32 + scol;  // per-lane
    unsigned short* sB0 = Bs + w * 512;
    unsigned short* sB1 = Bs + (4 + w) * 512;

    const unsigned short* arp[4];
    const unsigned short* brp[4];
    #pragma unroll
    for (int i = 0; i < 4; ++i) {
        arp[i] = As + (wm * 64 + i * 16 + lm) * 32 + lq * 8;
        brp[i] = Bs + (wn * 64 + i * 16 + lm) * 32 + lq * 8;
    }

    floatx4 acc[4][4] = {};

    // prefetch K-step 0
    float4 a00 = *(const float4*)(axg0);
    float4 a01 = *(const float4*)(axg0 + 4);
    float4 a10 = *(const float4*)(axg1);
    float4 a11 = *(const float4*)(axg1 + 4);

    for (int k0 = 0; k0 < K; k0 += 32) {
        __syncthreads();
        load_lds16(bg0 + k0, sB0);
        load_lds16(bg1 + k0, sB1);
        // stage the prefetched A tile (bf16)
        *(short8*)sA0w = cvt8(a00, a01);
        *(short8*)sA1w = cvt8(a10, a11);
        // prefetch next K-step (consumed after the next barrier — its HBM
        // latency overlaps the MFMA block below + next B-load drain)
        int kn = (k0 + 32 < K) ? k0 + 32 : 0;
        a00 = *(const float4*)(axg0 + kn);
        a01 = *(const float4*)(axg0 + kn + 4);
        a10 = *(const float4*)(axg1 + kn);
        a11 = *(const float4*)(axg1 + kn + 4);
        __syncthreads();

        short8 af[4], bf8[4];
        #pragma unroll
        for (int i = 0; i < 4; ++i) {
            af[i]  = *(const short8*)arp[i];
            bf8[i] = *(const short8*)brp[i];
        }
        #pragma unroll
        for (int mi = 0; mi < 4; ++mi)
            #pragma unroll
            for (int ni = 0; ni < 4; ++ni)
                acc[mi][ni] = __builtin_amdgcn_mfma_f32_16x16x32_bf16(
                    af[mi], bf8[ni], acc[mi][ni], 0, 0, 0);
    }

    float bv[4];
    #pragma unroll
    for (int ni = 0; ni < 4; ++ni) bv[ni] = bias[n0 + wn * 64 + ni * 16 + lm];

    #pragma unroll
    for (int mi = 0; mi < 4; ++mi) {
        int rbase = m0 + wm * 64 + mi * 16 + lq * 4;
        #pragma unroll
        for (int ni = 0; ni < 4; ++ni) {
            int cc = n0 + wn * 64 + ni * 16 + lm;
            #pragma unroll
            for (int r = 0; r < 4; ++r) {
                float v = fmaxf(acc[mi][ni][r] + bv[ni], 0.f);
                C[(size_t)(rbase + r) * ldc + cc] = f2bf(v);
            }
        }
    }
}

// ---------------------------------------------------------------------------
// 128x128-tile GEMM (m97 structure), bf16 A and B: C = relu(A@Bt^T + bias).
// ---------------------------------------------------------------------------
__global__ __launch_bounds__(256) void gemm_bt_kernel(
        const unsigned short* __restrict__ A,
        const unsigned short* __restrict__ Bt,
        const float* __restrict__ bias,
        unsigned short* __restrict__ C,
        int K, int lda, int ldc) {
    __shared__ unsigned short As[128 * 32];
    __shared__ unsigned short Bs[128 * 32];

    const int m0 = blockIdx.y * 128;
    const int n0 = blockIdx.x * 128;
    const int t    = threadIdx.x;
    const int lane = t & 63;
    const int w    = t >> 6;
    const int wm   = w >> 1;
    const int wn   = w & 1;
    const int lm   = lane & 15;
    const int lq   = lane >> 4;

    const int srow = lane >> 2;
    const int scol = (lane & 3) * 8;
    const unsigned short* ag0 = A  + (size_t)(m0 + w * 16 + srow) * lda + scol;
    const unsigned short* ag1 = A  + (size_t)(m0 + (4 + w) * 16 + srow) * lda + scol;
    const unsigned short* bg0 = Bt + (size_t)(n0 + w * 16 + srow) * K + scol;
    const unsigned short* bg1 = Bt + (size_t)(n0 + (4 + w) * 16 + srow) * K + scol;
    unsigned short* sA0 = As + w * 512;
    unsigned short* sA1 = As + (4 + w) * 512;
    unsigned short* sB0 = Bs + w * 512;
    unsigned short* sB1 = Bs + (4 + w) * 512;

    const unsigned short* arp[4];
    const unsigned short* brp[4];
    #pragma unroll
    for (int i = 0; i < 4; ++i) {
        arp[i] = As + (wm * 64 + i * 16 + lm) * 32 + lq * 8;
        brp[i] = Bs + (wn * 64 + i * 16 + lm) * 32 + lq * 8;
    }

    floatx4 acc[4][4] = {};

    for (int k0 = 0; k0 < K; k0 += 32) {
        __syncthreads();
        load_lds16(ag0 + k0, sA0);
        load_lds16(ag1 + k0, sA1);
        load_lds16(bg0 + k0, sB0);
        load_lds16(bg1 + k0, sB1);
        __syncthreads();

        short8 af[4], bf8[4];
        #pragma unroll
        for (int i = 0; i < 4; ++i) {
            af[i]  = *(const short8*)arp[i];
            bf8[i] = *(const short8*)brp[i];
        }
        #pragma unroll
        for (int mi = 0; mi < 4; ++mi)
            #pragma unroll
            for (int ni = 0; ni < 4; ++ni)
                acc[mi][ni] = __builtin_amdgcn_mfma_f32_16x16x32_bf16(
                    af[mi], bf8[ni], acc[mi][ni], 0, 0, 0);
    }

    float bv[4];
    #pragma unroll
    for (int ni = 0; ni < 4; ++ni) bv[ni] = bias[n0 + wn * 64 + ni * 16 + lm];

    #pragma unroll
    for (int mi = 0; mi < 4; ++mi) {
        int rbase = m0 + wm * 64 + mi * 16 + lq * 4;
        #pragma unroll
        for (int ni = 0; ni < 4; ++ni) {
            int cc = n0 + wn * 64 + ni * 16 + lm;
            #pragma unroll
            for (int r = 0; r < 4; ++r) {
                float v = fmaxf(acc[mi][ni][r] + bv[ni], 0.f);
                C[(size_t)(rbase + r) * ldc + cc] = f2bf(v);
            }
        }
    }
}

// ---------------------------------------------------------------------------
// head: one wave per row, 16B/lane coalesced, shuffle-reduce 6 sums.
// ---------------------------------------------------------------------------
__global__ void head_kernel(const unsigned short* __restrict__ h,
                            const float* __restrict__ w3,
                            const float* __restrict__ b3,
                            float* __restrict__ out) {
    int row = blockIdx.x * 4 + (threadIdx.x >> 6);
    int lane = threadIdx.x & 63;
    const unsigned short* hp = h + (size_t)row * 512 + lane * 8;
    ushort4 ha = *(const ushort4*)(hp);
    ushort4 hb = *(const ushort4*)(hp + 4);
    float hv[8] = {bf2f(ha.x), bf2f(ha.y), bf2f(ha.z), bf2f(ha.w),
                   bf2f(hb.x), bf2f(hb.y), bf2f(hb.z), bf2f(hb.w)};
    const float* wp = w3 + lane * 48;
    float s[6] = {0.f, 0.f, 0.f, 0.f, 0.f, 0.f};
    #pragma unroll
    for (int j = 0; j < 8; ++j)
        #pragma unroll
        for (int a = 0; a < 6; ++a)
            s[a] += hv[j] * wp[j * 6 + a];
    #pragma unroll
    for (int a = 0; a < 6; ++a)
        #pragma unroll
        for (int off = 32; off; off >>= 1)
            s[a] += __shfl_down(s[a], off, 64);
    if (lane == 0) {
        #pragma unroll
        for (int a = 0; a < 6; ++a)
            out[(size_t)row * 6 + a] = fmaxf(s[a] + b3[a], 0.f);
    }
}

// ---------------------------------------------------------------------------
extern "C" void kernel_launch(void* const* d_in, const int* in_sizes, int n_in,
                              void* d_out, int out_size, void* d_ws, size_t ws_size,
                              hipStream_t stream) {
    const float* x        = (const float*)d_in[0];
    const float* gpe_mask = (const float*)d_in[1];
    const float* gpe_w    = (const float*)d_in[2];
    const float* gpe_b    = (const float*)d_in[3];
    const float* gpi_mask = (const float*)d_in[4];
    const float* gpi_w    = (const float*)d_in[5];
    const float* gpi_b    = (const float*)d_in[6];
    const float* w1       = (const float*)d_in[7];
    const float* b1       = (const float*)d_in[8];
    const float* w2       = (const float*)d_in[9];
    const float* b2       = (const float*)d_in[10];
    const float* w3       = (const float*)d_in[11];
    const float* b3       = (const float*)d_in[12];
    float* out = (float*)d_out;

    // workspace carve (bytes), total ~56.1 MB
    char* ws = (char*)d_ws;
    unsigned short* h1        = (unsigned short*)(ws);              // B*512
    unsigned short* h2        = (unsigned short*)(ws + 16777216);   // B*512
    unsigned short* wi_topnt  = (unsigned short*)(ws + 33554432);   // [i][u] 1536^2
    unsigned short* wi_bot    = (unsigned short*)(ws + 38273024);   // [u][j] 1536^2
    unsigned short* we_nt     = (unsigned short*)(ws + 42991616);   // [i][j] 1536^2
    unsigned short* wc_nt     = (unsigned short*)(ws + 47710208);   // [i][u] 1536^2
    unsigned short* w1t       = (unsigned short*)(ws + 52428800);   // [n][u] 512x1536
    unsigned short* w2t       = (unsigned short*)(ws + 54001664);   // [n][k] 512x512
    unsigned short* w1ct      = (unsigned short*)(ws + 54525952);   // [n][i] 512x1536
    float*          bc        = (float*)(ws + 56098816);            // [1536]
    float*          b1c       = (float*)(ws + 56104960);            // [512]

    // ---- weight preps ----
    prep_all_kernel<<<dim3(1984), dim3(256), 0, stream>>>(
        gpe_w, gpe_mask, gpi_w, gpi_mask, w1, w2,
        wi_topnt, wi_bot, we_nt, w1t, w2t);

    // ---- combine1 + bias-fold1 ----
    combo1_kernel<<<dim3(960), dim3(256), 0, stream>>>(
        we_nt, wi_bot, wi_topnt, wc_nt, gpe_b, gpi_b, bc);

    // ---- combine2 + bias-fold2 ----
    combo2_kernel<<<dim3(320), dim3(256), 0, stream>>>(
        w1t, wc_nt, w1ct, bc, b1, b1c);

    // ---- batch chain ----
    // h1 = relu(x @ W1c + b1c)  (f32 x, fused cvt, 1-step reg prefetch)
    gemm_a32_kernel<<<dim3(4, 128), dim3(256), 0, stream>>>(
        x, w1ct, b1c, h1, 1536, 1536, 512);
    // h2 = relu(h1 @ w2 + b2)
    gemm_bt_kernel<<<dim3(4, 128), dim3(256), 0, stream>>>(
        h1, w2t, b2, h2, 512, 512, 512);
    // out = relu(h2 @ w3 + b3)
    head_kernel<<<dim3(16384 / 4), dim3(256), 0, stream>>>(h2, w3, b3, out);
}